// Round 8
// baseline (231.917 us; speedup 1.0000x reference)
//
#include <hip/hip_runtime.h>

// Problem constants (B,N,M,D) = (16,1024,4096,256), all fp32.
// Strategy: cross-GEMM on matrix cores via exact 2-term fp16 split
// (e = ae+be, t*2^17 = at+bt), 3 MFMA products ae*at + ae*bt + be*at,
// splits precomputed (round 7). Round 8: (a) LDS rows 72B (LDH=36) with
// b64 accesses -> provably conflict-free frag reads (old 80B rows cost
// exactly 2^24 conflict cycles = 8/read); (b) double-buffered LDS +
// register prefetch + ONE barrier per chunk (write(i)->bar->load(i+1)->
// compute(i)); rendezvous: a wave at write(i+1,B') passed barrier_i,
// which all waves reach only after compute(i-1,B') finished.
// Numerics FROZEN from rounds 6/7 (absmax=0): identical split values,
// identical MFMA product/k order, identical epilogue
// d2 = fl(fl(esq - 2*cross) + tsq), np-pairwise esq/tsq.

typedef _Float16 half4 __attribute__((ext_vector_type(4)));
typedef _Float16 half8 __attribute__((ext_vector_type(8)));
typedef float f32x4 __attribute__((ext_vector_type(4)));

constexpr int B_ = 16, N_ = 1024, M_ = 4096, D_ = 256;
constexpr int ROWS = B_ * N_;      // 16384 query rows
constexpr int BR = 128;            // rows per block
constexpr int BC = 128;            // cols per col-tile
constexpr int NCT = 4;             // col-tiles per block
constexpr int CS = 8;              // col splits (blockIdx.y)
constexpr int CPB = BC * NCT;      // 512 cols per block
constexpr int KC = 32;             // k per chunk = one 16x16x32 MFMA-K
constexpr int NCH = NCT * (D_ / KC); // 32 chunks per block
constexpr int LDH = 36;            // LDS halfs/row: 32 data + 4 pad (72B rows)
constexpr int NPART = CS * 2;      // 16 partials per row (2 col-half waves)
constexpr float TSCALE = 131072.0f;        // 2^17 (exact)
constexpr float INV2 = 1.52587890625e-05f; // 2^-16: acc*2^-16 == 2*cross, exact

// LDS b64 helpers (72B rows are only 8B-aligned -> compiler cannot legally
// re-merge these into b128; keeps the conflict-free 2-bank-span pattern).
__device__ inline void st8(_Float16* p, half8 v) {
    half4 a = {v[0], v[1], v[2], v[3]};
    half4 b = {v[4], v[5], v[6], v[7]};
    *reinterpret_cast<half4*>(p) = a;
    *reinterpret_cast<half4*>(p + 4) = b;
}
__device__ inline half8 ld8(const _Float16* p) {
    half4 a = *reinterpret_cast<const half4*>(p);
    half4 b = *reinterpret_cast<const half4*>(p + 4);
    return (half8){a[0], a[1], a[2], a[3], b[0], b[1], b[2], b[3]};
}

// ---------------------------------------------------------------------------
// Kernel 0: one-time hi/lo fp16 split of E and T (T scaled by 2^17, exact).
// ---------------------------------------------------------------------------
__global__ void split_kernel(const float* __restrict__ E, const float* __restrict__ T,
                             _Float16* __restrict__ Ehi, _Float16* __restrict__ Elo,
                             _Float16* __restrict__ Thi, _Float16* __restrict__ Tlo) {
    int idx = blockIdx.x * blockDim.x + threadIdx.x;
    int row = idx >> 5;            // 32 threads per 256-elem row
    int c8 = (idx & 31) * 8;
    if (row >= ROWS + M_) return;
    const float* src;
    _Float16 *hi, *lo;
    size_t off;
    float scale;
    if (row < ROWS) {
        off = (size_t)row * D_ + c8;
        src = E + off; hi = Ehi; lo = Elo; scale = 1.0f;
    } else {
        off = (size_t)(row - ROWS) * D_ + c8;
        src = T + off; hi = Thi; lo = Tlo; scale = TSCALE;
    }
    float x[8];
    *reinterpret_cast<float4*>(&x[0]) = *reinterpret_cast<const float4*>(src);
    *reinterpret_cast<float4*>(&x[4]) = *reinterpret_cast<const float4*>(src + 4);
    half8 h, l;
    #pragma unroll
    for (int j = 0; j < 8; j++) {
        float xs = x[j] * scale;               // exact for T (pow2), 1.0 for E
        _Float16 hh = (_Float16)xs;            // RN
        h[j] = hh;
        l[j] = (_Float16)(xs - (float)hh);
    }
    *reinterpret_cast<half8*>(hi + off) = h;
    *reinterpret_cast<half8*>(lo + off) = l;
}

// ---------------------------------------------------------------------------
// Kernel 1 (FROZEN): row sum-of-squares, numpy pairwise bit-exact for n=256.
// ---------------------------------------------------------------------------
__global__ void rowsq_kernel(const float* __restrict__ E, const float* __restrict__ T,
                             float* __restrict__ esq, float* __restrict__ tsq) {
    int gt = blockIdx.x * blockDim.x + threadIdx.x;
    int row = gt >> 4;
    int l = gt & 15;
    if (row >= ROWS + M_) return;
    const float* src = (row < ROWS) ? (E + (size_t)row * D_)
                                    : (T + (size_t)(row - ROWS) * D_);
    const float* p = src + (l >> 3) * 128 + (l & 7);
    float r = __fmul_rn(p[0], p[0]);
    #pragma unroll
    for (int i = 1; i < 16; i++) {
        float x = p[8 * i];
        r = __fadd_rn(r, __fmul_rn(x, x));
    }
    float u = __fadd_rn(r, __shfl_xor(r, 1, 64));
    float v = __fadd_rn(u, __shfl_xor(u, 2, 64));
    float w = __fadd_rn(v, __shfl_xor(v, 4, 64));
    float s = __fadd_rn(w, __shfl_xor(w, 8, 64));
    if (l == 0) {
        if (row < ROWS) esq[row] = s;
        else            tsq[row - ROWS] = s;
    }
}

// ---------------------------------------------------------------------------
// Kernel 2: MFMA fused GEMM + argmin of d2 = fl(fl(esq - 2*cross) + tsq).
// 256 threads = 4 waves (2x2 of 64x64); wave = 4x4 frags of 16x16x32_f16.
// Double-buffered LDS, one barrier/chunk, register prefetch of chunk i+1.
// ---------------------------------------------------------------------------
__global__ __launch_bounds__(256) void score_kernel(
    const _Float16* __restrict__ Ehi_g, const _Float16* __restrict__ Elo_g,
    const _Float16* __restrict__ Thi_g, const _Float16* __restrict__ Tlo_g,
    const float* __restrict__ esq, const float* __restrict__ tsq,
    float2* __restrict__ part) {
    __shared__ _Float16 Eh[2][BR][LDH];
    __shared__ _Float16 El[2][BR][LDH];
    __shared__ _Float16 Th[2][BC][LDH];
    __shared__ _Float16 Tl[2][BC][LDH];

    const int tid = threadIdx.x;
    const int w  = tid >> 6;       // wave 0..3
    const int l  = tid & 63;
    const int wr = w >> 1;         // row half (0/1)
    const int wc = w & 1;          // col half (0/1)
    const int q  = l >> 4;         // lane quarter
    const int cl = l & 15;         // col-in-frag
    const int row0 = blockIdx.x * BR;
    const int cs = blockIdx.y;
    const int colB = cs * CPB;

    const int srow  = tid >> 1;         // staging row 0..127
    const int skoff = (tid & 1) * 16;   // staging k offset 0/16

    // Per-lane esq values for the 16 (fr,reg) row slots.
    float er[16];
    #pragma unroll
    for (int fr = 0; fr < 4; fr++)
        #pragma unroll
        for (int rg = 0; rg < 4; rg++)
            er[fr * 4 + rg] = esq[row0 + wr * 64 + fr * 16 + q * 4 + rg];

    float best[16];
    int   bidx[16];
    #pragma unroll
    for (int i = 0; i < 16; i++) { best[i] = 3.4e38f; bidx[i] = 0; }

    // Prefetch registers for one chunk (8 x half8 = 32 VGPR).
    half8 rE0, rE1, rF0, rF1, rG0, rG1, rH0, rH1;
    const size_t eo_base = (size_t)(row0 + srow) * D_ + skoff;
    #define LOADREGS(ch)                                                        \
        {                                                                       \
            const int ct_ = (ch) >> 3, kc_ = ((ch) & 7) * KC;                   \
            const size_t eo = eo_base + kc_;                                    \
            const size_t to = (size_t)(colB + ct_ * BC + srow) * D_ + kc_ + skoff; \
            rE0 = *reinterpret_cast<const half8*>(Ehi_g + eo);                  \
            rE1 = *reinterpret_cast<const half8*>(Ehi_g + eo + 8);              \
            rF0 = *reinterpret_cast<const half8*>(Elo_g + eo);                  \
            rF1 = *reinterpret_cast<const half8*>(Elo_g + eo + 8);              \
            rG0 = *reinterpret_cast<const half8*>(Thi_g + to);                  \
            rG1 = *reinterpret_cast<const half8*>(Thi_g + to + 8);              \
            rH0 = *reinterpret_cast<const half8*>(Tlo_g + to);                  \
            rH1 = *reinterpret_cast<const half8*>(Tlo_g + to + 8);              \
        }

    LOADREGS(0);
    f32x4 acc[4][4];
    int buf = 0;

    for (int ch = 0; ch < NCH; ++ch) {
        if ((ch & 7) == 0) {
            #pragma unroll
            for (int i = 0; i < 4; i++)
                #pragma unroll
                for (int j = 0; j < 4; j++)
                    acc[i][j] = (f32x4){0.f, 0.f, 0.f, 0.f};
        }
        // Stage prefetched regs into LDS buffer `buf` (b64 stores).
        st8(&Eh[buf][srow][skoff], rE0); st8(&Eh[buf][srow][skoff + 8], rE1);
        st8(&El[buf][srow][skoff], rF0); st8(&El[buf][srow][skoff + 8], rF1);
        st8(&Th[buf][srow][skoff], rG0); st8(&Th[buf][srow][skoff + 8], rG1);
        st8(&Tl[buf][srow][skoff], rH0); st8(&Tl[buf][srow][skoff + 8], rH1);
        __syncthreads();
        // Issue next chunk's global loads; latency hides under compute.
        if (ch < NCH - 1) LOADREGS(ch + 1);

        // Frags (b64 pair reads, conflict-free spans); MFMA order FROZEN:
        // hi*hi, hi*Tlo, Elo*hi.
        half8 ah[4], bh[4], tmp[4];
        #pragma unroll
        for (int f = 0; f < 4; f++)
            ah[f] = ld8(&Eh[buf][wr * 64 + f * 16 + cl][q * 8]);
        #pragma unroll
        for (int f = 0; f < 4; f++)
            bh[f] = ld8(&Th[buf][wc * 64 + f * 16 + cl][q * 8]);
        #pragma unroll
        for (int i = 0; i < 4; i++)
            #pragma unroll
            for (int j = 0; j < 4; j++)
                acc[i][j] = __builtin_amdgcn_mfma_f32_16x16x32_f16(ah[i], bh[j], acc[i][j], 0, 0, 0);
        #pragma unroll
        for (int f = 0; f < 4; f++)
            tmp[f] = ld8(&Tl[buf][wc * 64 + f * 16 + cl][q * 8]);
        #pragma unroll
        for (int i = 0; i < 4; i++)
            #pragma unroll
            for (int j = 0; j < 4; j++)
                acc[i][j] = __builtin_amdgcn_mfma_f32_16x16x32_f16(ah[i], tmp[j], acc[i][j], 0, 0, 0);
        #pragma unroll
        for (int f = 0; f < 4; f++)
            tmp[f] = ld8(&El[buf][wr * 64 + f * 16 + cl][q * 8]);
        #pragma unroll
        for (int i = 0; i < 4; i++)
            #pragma unroll
            for (int j = 0; j < 4; j++)
                acc[i][j] = __builtin_amdgcn_mfma_f32_16x16x32_f16(tmp[i], bh[j], acc[i][j], 0, 0, 0);

        // Epilogue at the end of each col-tile (every 8th chunk).
        if ((ch & 7) == 7) {
            const int col0 = colB + (ch >> 3) * BC;
            #pragma unroll
            for (int fc = 0; fc < 4; fc++) {
                const int col = col0 + wc * 64 + fc * 16 + cl;
                const float tc = tsq[col];
                #pragma unroll
                for (int fr = 0; fr < 4; fr++)
                    #pragma unroll
                    for (int rg = 0; rg < 4; rg++) {
                        const float c2 = acc[fr][fc][rg] * INV2;  // exact scale
                        const float d1 = __fsub_rn(er[fr * 4 + rg], c2);
                        const float d2 = __fadd_rn(d1, tc);
                        const int s = fr * 4 + rg;
                        if (d2 < best[s]) { best[s] = d2; bidx[s] = col; }
                    }
            }
        }
        buf ^= 1;
    }

    // Cross-lane reduce within each 16-lane quarter (same rows, diff cols).
    #pragma unroll
    for (int s = 0; s < 16; s++) {
        float v = best[s]; int i = bidx[s];
        #pragma unroll
        for (int off = 1; off < 16; off <<= 1) {
            float ov = __shfl_xor(v, off, 64);
            int   oi = __shfl_xor(i, off, 64);
            if (ov < v || (ov == v && oi < i)) { v = ov; i = oi; }
        }
        if (cl == 0) {
            const int row = row0 + wr * 64 + (s >> 2) * 16 + q * 4 + (s & 3);
            part[(size_t)row * NPART + cs * 2 + wc] = make_float2(v, __int_as_float(i));
        }
    }
}

// ---------------------------------------------------------------------------
// Kernel 3: reduce NPART partials per row (min value, min index on ties),
// gather quant = templat[idx] (bitwise copy), write zidx as float.
// ---------------------------------------------------------------------------
__global__ void gather_kernel(const float* __restrict__ T, const float2* __restrict__ part,
                              float* __restrict__ quant, float* __restrict__ zout) {
    int gt = blockIdx.x * blockDim.x + threadIdx.x;
    int w = gt >> 6, lane = gt & 63;
    if (w >= ROWS) return;
    float2 p = part[(size_t)w * NPART];
    float v = p.x; int idx = __float_as_int(p.y);
    #pragma unroll
    for (int c = 1; c < NPART; c++) {
        float2 q = part[(size_t)w * NPART + c];
        int qi = __float_as_int(q.y);
        if (q.x < v || (q.x == v && qi < idx)) { v = q.x; idx = qi; }
    }
    float4 t = *reinterpret_cast<const float4*>(T + (size_t)idx * D_ + lane * 4);
    *reinterpret_cast<float4*>(quant + (size_t)w * D_ + lane * 4) = t;
    if (lane == 0) zout[w] = (float)idx;
}

// ---------------------------------------------------------------------------
extern "C" void kernel_launch(void* const* d_in, const int* in_sizes, int n_in,
                              void* d_out, int out_size, void* d_ws, size_t ws_size,
                              hipStream_t stream) {
    const float* E = (const float*)d_in[0];   // encode  (B,N,D)
    const float* T = (const float*)d_in[1];   // templat (M,D)
    float* quant = (float*)d_out;                        // (B,N,D) fp32
    float* zout  = quant + (size_t)ROWS * D_;            // (B,N) idx as fp32

    // ws layout: esq[ROWS], tsq[M], part[ROWS*NPART], fp16 Ehi/Elo/Thi/Tlo.
    float* esq   = (float*)d_ws;
    float* tsq   = esq + ROWS;
    float2* part = (float2*)(tsq + M_);
    _Float16* Ehi = (_Float16*)(part + (size_t)ROWS * NPART);
    _Float16* Elo = Ehi + (size_t)ROWS * D_;
    _Float16* Thi = Elo + (size_t)ROWS * D_;
    _Float16* Tlo = Thi + (size_t)M_ * D_;

    hipLaunchKernelGGL(split_kernel, dim3((ROWS + M_) * 32 / 256), dim3(256), 0, stream,
                       E, T, Ehi, Elo, Thi, Tlo);
    hipLaunchKernelGGL(rowsq_kernel, dim3((ROWS + M_) * 16 / 256), dim3(256), 0, stream, E, T, esq, tsq);
    hipLaunchKernelGGL(score_kernel, dim3(ROWS / BR, CS), dim3(256), 0, stream,
                       Ehi, Elo, Thi, Tlo, esq, tsq, part);
    hipLaunchKernelGGL(gather_kernel, dim3(ROWS * 64 / 256), dim3(256), 0, stream, T, part, quant, zout);
}